// Round 10
// baseline (374.334 us; speedup 1.0000x reference)
//
#include <hip/hip_runtime.h>

typedef __bf16 bf16x8_t __attribute__((ext_vector_type(8)));
typedef float f32x4_t __attribute__((ext_vector_type(4)));

#define AS1 __attribute__((address_space(1)))
#define AS3 __attribute__((address_space(3)))

__device__ __forceinline__ unsigned short f2b(float f) {
    unsigned u = __builtin_bit_cast(unsigned, f);
    u += 0x7fffu + ((u >> 16) & 1u);
    return (unsigned short)(u >> 16);
}
__device__ __forceinline__ float b2f(unsigned short s) {
    return __builtin_bit_cast(float, (unsigned)s << 16);
}

// ---------------------------------------------------------------------------
// fp32 -> bf16 convert, 4 elems/thread
// ---------------------------------------------------------------------------
__global__ __launch_bounds__(256) void k_f2b(const float* __restrict__ in,
                                             unsigned short* __restrict__ out,
                                             int n4) {
    int i = blockIdx.x * 256 + threadIdx.x;
    if (i >= n4) return;
    float4 v = reinterpret_cast<const float4*>(in)[i];
    ushort4 o;
    o.x = f2b(v.x); o.y = f2b(v.y); o.z = f2b(v.z); o.w = f2b(v.w);
    reinterpret_cast<ushort4*>(out)[i] = o;
}

// ---------------------------------------------------------------------------
// Occupancy + intensity NT-GEMM. C-tile 256(M) x 128(N), BK=32, 256 threads
// = 4 waves (2M x 2N), wave = 128x64 = 8x4 frags of 16x16x32 bf16 MFMA
// (acc 128 VGPR; ~190 total < 256 cap at launch_bounds(256,2)).
// LDS: 3 buffers x 24KB {A 256x32=16KB, B 128x32=8KB} = 72KB -> 2 blocks/CU:
// independent blocks fill each other's barrier/vmcnt stalls (r9's win), and
// the 128x64 wave tile gives 42.7 FLOP per LDS byte (r9's 64x64 = 32, below
// the ~40 needed at measured ds_read_b128 throughput -> r9 was LDS-BW-bound).
// Swizzle for 64B rows (r9 had 8-way conflicts, 8.4M cy): read byte-in-row
// (g*16) ^ ((row&3)<<4); staging pre-swizzles the global source column
// ((t&3)*16) ^ (((t>>2)&3)<<4) with a linear LDS dest (both-sides rule).
// Derivation: 16B-slot group = (row*4 + (g^(row&3))) & 7 covers all 8 bank
// groups uniformly (8 lanes each) -> conflict-free 1KB wave read.
// Schedule: r9's counted-vmcnt 3-buffer loop; 6 loads/tile -> vmcnt(6);
// stage t+2 right after the barrier (its buffer's readers passed at t-1);
// wait BEFORE the barrier; never vmcnt(0) mid-loop.
// ---------------------------------------------------------------------------
#define STAGE(tt, bb) do {                                                     \
    char* dst_ = smem + (bb) * 24576;                                          \
    const size_t kof_ = (size_t)(tt) * 32;                                     \
    _Pragma("unroll")                                                          \
    for (int i_ = 0; i_ < 4; ++i_)                                             \
        __builtin_amdgcn_global_load_lds(                                      \
            (const AS1 void*)(pA + kof_ + (size_t)(64 * i_) * lda),            \
            (AS3 void*)(dst_ + wave * 1024 + i_ * 4096), 16, 0, 0);            \
    _Pragma("unroll")                                                          \
    for (int i_ = 0; i_ < 2; ++i_)                                             \
        __builtin_amdgcn_global_load_lds(                                      \
            (const AS1 void*)(pB + kof_ + (size_t)(64 * i_) * ldb),            \
            (AS3 void*)(dst_ + 16384 + wave * 1024 + i_ * 4096), 16, 0, 0);    \
} while (0)

__device__ __forceinline__ void gemm_mainloop(
    const unsigned short* __restrict__ A, int lda,
    const unsigned short* __restrict__ B, int ldb,
    int K, char* smem, f32x4_t acc[8][4]) {
    const int tid = threadIdx.x;
    const int wave = tid >> 6, lane = tid & 63;
    const int wm = wave >> 1, wn = wave & 1;
    const int fr = lane & 15, g = lane >> 4;

    // staging: thread t covers 16B slots {t + 256*i}; row = wave*16+(lane>>2)
    // (+64*i); source col pre-swizzled, LDS dest linear.
    const int scolB = ((lane & 3) * 16) ^ (((lane >> 2) & 3) << 4);
    const unsigned short* pA = A + (size_t)(wave * 16 + (lane >> 2)) * lda + (scolB >> 1);
    const unsigned short* pB = B + (size_t)(wave * 16 + (lane >> 2)) * ldb + (scolB >> 1);

    // frag ds_read offsets: row*64 + ((g*16) ^ ((row&3)<<4)); row&3 == fr&3.
    int offA[8], offB[4];
#pragma unroll
    for (int mi = 0; mi < 8; ++mi)
        offA[mi] = (wm * 128 + mi * 16 + fr) * 64 + ((g * 16) ^ ((fr & 3) << 4));
#pragma unroll
    for (int ni = 0; ni < 4; ++ni)
        offB[ni] = 16384 + (wn * 64 + ni * 16 + fr) * 64 + ((g * 16) ^ ((fr & 3) << 4));

#pragma unroll
    for (int mi = 0; mi < 8; ++mi)
#pragma unroll
        for (int ni = 0; ni < 4; ++ni)
            acc[mi][ni] = (f32x4_t){0.f, 0.f, 0.f, 0.f};

    const int NT = K >> 5;   // K multiple of 64 -> NT >= 2

    STAGE(0, 0);
    STAGE(1, 1);

    int cb = 0;
    for (int t = 0; t < NT; ++t) {
        if (t + 1 < NT) asm volatile("s_waitcnt vmcnt(6)" ::: "memory");
        else            asm volatile("s_waitcnt vmcnt(0)" ::: "memory");
        asm volatile("s_barrier" ::: "memory");
        if (t + 2 < NT) {
            int sb = cb + 2; if (sb >= 3) sb -= 3;
            STAGE(t + 2, sb);   // safe: sb last read at t-1, readers passed barrier
        }
        const char* rb = smem + cb * 24576;
        bf16x8_t af[8], bfv[4];
#pragma unroll
        for (int mi = 0; mi < 8; ++mi)
            af[mi] = *reinterpret_cast<const bf16x8_t*>(rb + offA[mi]);
#pragma unroll
        for (int ni = 0; ni < 4; ++ni)
            bfv[ni] = *reinterpret_cast<const bf16x8_t*>(rb + offB[ni]);
        __builtin_amdgcn_s_setprio(1);
#pragma unroll
        for (int mi = 0; mi < 8; ++mi)
#pragma unroll
            for (int ni = 0; ni < 4; ++ni)
                acc[mi][ni] = __builtin_amdgcn_mfma_f32_16x16x32_bf16(
                    af[mi], bfv[ni], acc[mi][ni], 0, 0, 0);
        __builtin_amdgcn_s_setprio(0);
        cb = (cb + 1 == 3) ? 0 : cb + 1;
    }
}

// Epilogue: acc[mi][ni][j] -> row = tm + wm*128 + mi*16 + (lane>>4)*4 + j
//                            col = tn + wn*64 + ni*16 + (lane&15)
#define EPILOGUE_IDX                                            \
    const int lane = threadIdx.x & 63, wave = threadIdx.x >> 6; \
    const int e_r0 = (wave >> 1) * 128 + (lane >> 4) * 4;       \
    const int e_c0 = (wave & 1) * 64 + (lane & 15);

#define EPILOGUE_LOOP(...)                                      \
    _Pragma("unroll") for (int mi = 0; mi < 8; ++mi)            \
    _Pragma("unroll") for (int ni = 0; ni < 4; ++ni)            \
    _Pragma("unroll") for (int j = 0; j < 4; ++j) { __VA_ARGS__ }

// Interleaved q/k layout: per batch z (8 total), base elem z*4194304:
//   q_z[2048][1024] at +0, k_z[2048][1024] at +2097152.
// Softmax output P_z[2048][2048] bf16 later overlays exactly this region.

// ---------------------------------------------------------------------------
// QKV GEMM, Q/K half: M=16384 tokens, N=2048 (w_qkv rows 0..2047), K=1024
// ---------------------------------------------------------------------------
__global__ __launch_bounds__(256, 2) void k_gemm_qkv_qk(
    const unsigned short* __restrict__ x, const unsigned short* __restrict__ w,
    unsigned short* __restrict__ qk) {
    __shared__ __align__(16) char smem[73728];
    const size_t tm = (size_t)blockIdx.x * 256, tn = (size_t)blockIdx.y * 128;
    f32x4_t acc[8][4];
    gemm_mainloop(x + tm * 1024, 1024, w + tn * 1024, 1024, 1024, smem, acc);
    EPILOGUE_IDX
    EPILOGUE_LOOP(
        size_t m = tm + e_r0 + mi * 16 + j;
        size_t z = m >> 11;
        size_t nloc = m & 2047;
        int n = (int)tn + e_c0 + ni * 16;
        unsigned short v = f2b(acc[mi][ni][j]);
        size_t base = z * 4194304 + nloc * 1024;
        if (n < 1024) qk[base + n] = v;
        else          qk[base + 2097152 + (n - 1024)] = v;
    )
}

// ---------------------------------------------------------------------------
// QKV GEMM, V^T half (operands swapped): M=1024 (v-weight rows), N=16384
// tokens, K=1024.  vt[c][token] = v[token][c], coalesced stores.
// ---------------------------------------------------------------------------
__global__ __launch_bounds__(256, 2) void k_gemm_vt(
    const unsigned short* __restrict__ wv, const unsigned short* __restrict__ x,
    unsigned short* __restrict__ vt) {
    __shared__ __align__(16) char smem[73728];
    const size_t tm = (size_t)blockIdx.x * 256, tn = (size_t)blockIdx.y * 128;
    f32x4_t acc[8][4];
    gemm_mainloop(wv + tm * 1024, 1024, x + tn * 1024, 1024, 1024, smem, acc);
    EPILOGUE_IDX
    EPILOGUE_LOOP(
        size_t m = tm + e_r0 + mi * 16 + j;   // c
        size_t n = tn + e_c0 + ni * 16;       // token
        vt[m * 16384 + n] = f2b(acc[mi][ni][j]);
    )
}

// ---------------------------------------------------------------------------
// Scores: batch z = z0 + blockIdx.z; S[zlocal][nq][mk] = bf16((q·k)/32)
// ---------------------------------------------------------------------------
__global__ __launch_bounds__(256, 2) void k_gemm_scores(
    const unsigned short* __restrict__ qk, unsigned short* __restrict__ S, int z0) {
    __shared__ __align__(16) char smem[73728];
    const size_t z = z0 + blockIdx.z;
    const size_t tm = (size_t)blockIdx.x * 256, tn = (size_t)blockIdx.y * 128;
    const unsigned short* qz = qk + z * 4194304;
    const unsigned short* kz = qz + 2097152;
    f32x4_t acc[8][4];
    gemm_mainloop(qz + tm * 1024, 1024, kz + tn * 1024, 1024, 1024, smem, acc);
    EPILOGUE_IDX
    unsigned short* Sz = S + (size_t)blockIdx.z * 4194304;
    EPILOGUE_LOOP(
        size_t m = tm + e_r0 + mi * 16 + j;
        size_t n = tn + e_c0 + ni * 16;
        Sz[m * 2048 + n] = f2b(acc[mi][ni][j] * 0.03125f);
    )
}

// ---------------------------------------------------------------------------
// Row softmax: NZ*2048 rows x 2048, bf16 in -> bf16 out (P overlays q/k)
// One 16B vector (8 bf16) per thread.
// ---------------------------------------------------------------------------
__global__ __launch_bounds__(256) void k_softmax(const unsigned short* __restrict__ S,
                                                 unsigned short* __restrict__ qk,
                                                 int z0) {
    const size_t r = blockIdx.x;                 // row within chunk
    const int t = threadIdx.x, wv = t >> 6, ln = t & 63;
    const uint4 u = reinterpret_cast<const uint4*>(S + r * 2048)[t];
    float vals[8];
    vals[0] = b2f((unsigned short)(u.x & 0xffff)); vals[1] = b2f((unsigned short)(u.x >> 16));
    vals[2] = b2f((unsigned short)(u.y & 0xffff)); vals[3] = b2f((unsigned short)(u.y >> 16));
    vals[4] = b2f((unsigned short)(u.z & 0xffff)); vals[5] = b2f((unsigned short)(u.z >> 16));
    vals[6] = b2f((unsigned short)(u.w & 0xffff)); vals[7] = b2f((unsigned short)(u.w >> 16));

    float mx = vals[0];
#pragma unroll
    for (int i = 1; i < 8; ++i) mx = fmaxf(mx, vals[i]);
#pragma unroll
    for (int i = 32; i > 0; i >>= 1) mx = fmaxf(mx, __shfl_xor(mx, i, 64));
    __shared__ float red[8];
    if (ln == 0) red[wv] = mx;
    __syncthreads();
    mx = fmaxf(fmaxf(red[0], red[1]), fmaxf(red[2], red[3]));

    float ex[8], s = 0.f;
#pragma unroll
    for (int i = 0; i < 8; ++i) { ex[i] = __expf(vals[i] - mx); s += ex[i]; }
#pragma unroll
    for (int i = 32; i > 0; i >>= 1) s += __shfl_xor(s, i, 64);
    if (ln == 0) red[4 + wv] = s;
    __syncthreads();
    s = (red[4] + red[5]) + (red[6] + red[7]);
    float inv = 1.0f / s;

    uint4 o;
    o.x = (unsigned)f2b(ex[0] * inv) | ((unsigned)f2b(ex[1] * inv) << 16);
    o.y = (unsigned)f2b(ex[2] * inv) | ((unsigned)f2b(ex[3] * inv) << 16);
    o.z = (unsigned)f2b(ex[4] * inv) | ((unsigned)f2b(ex[5] * inv) << 16);
    o.w = (unsigned)f2b(ex[6] * inv) | ((unsigned)f2b(ex[7] * inv) << 16);

    const size_t zg = z0 + (r >> 11), nloc = r & 2047;
    reinterpret_cast<uint4*>(qk + zg * 4194304 + nloc * 2048)[t] = o;
}

// ---------------------------------------------------------------------------
// PV as O^T: batch z = z0+blockIdx.z, O^T[c][n] = sum_m vt[c][m] * P[n][m]
// M=1024 (c), N=2048 (n), K=2048.  Stores apply the swapaxes-reshape
// scramble o2[2c + (n>>10)][n&1023] = o[n][c] -> coalesced in n.
// ---------------------------------------------------------------------------
__global__ __launch_bounds__(256, 2) void k_gemm_pv(
    const unsigned short* __restrict__ vt, const unsigned short* __restrict__ qk,
    unsigned short* __restrict__ ob, int z0) {
    __shared__ __align__(16) char smem[73728];
    const size_t z = z0 + blockIdx.z;
    const size_t tm = (size_t)blockIdx.x * 256, tn = (size_t)blockIdx.y * 128;
    const unsigned short* P = qk + z * 4194304;
    f32x4_t acc[8][4];
    gemm_mainloop(vt + tm * 16384 + z * 2048, 16384,
                  P + tn * 2048, 2048, 2048, smem, acc);
    EPILOGUE_IDX
    unsigned short* oz = ob + z * 2097152;
    EPILOGUE_LOOP(
        size_t m = tm + e_r0 + mi * 16 + j;   // c
        size_t n = tn + e_c0 + ni * 16;       // token n within batch
        oz[(2 * m + (n >> 10)) * 1024 + (n & 1023)] = f2b(acc[mi][ni][j]);
    )
}

// ---------------------------------------------------------------------------
// Proj: out[m][d] = sum_j o2[m][j] * w_proj[d][j] + b_proj[d], fp32 out
// M=16384, N=1024, K=1024
// ---------------------------------------------------------------------------
__global__ __launch_bounds__(256, 2) void k_gemm_proj(
    const unsigned short* __restrict__ o2, const unsigned short* __restrict__ w,
    const float* __restrict__ bias, float* __restrict__ out) {
    __shared__ __align__(16) char smem[73728];
    const size_t tm = (size_t)blockIdx.x * 256, tn = (size_t)blockIdx.y * 128;
    f32x4_t acc[8][4];
    gemm_mainloop(o2 + tm * 1024, 1024, w + tn * 1024, 1024, 1024, smem, acc);
    EPILOGUE_IDX
    EPILOGUE_LOOP(
        size_t m = tm + e_r0 + mi * 16 + j;
        size_t n = tn + e_c0 + ni * 16;
        out[m * 1024 + n] = acc[mi][ni][j] + bias[n];
    )
}

// ---------------------------------------------------------------------------
extern "C" void kernel_launch(void* const* d_in, const int* in_sizes, int n_in,
                              void* d_out, int out_size, void* d_ws, size_t ws_size,
                              hipStream_t stream) {
    const float* x     = (const float*)d_in[0];
    const float* wqkv  = (const float*)d_in[1];
    const float* wproj = (const float*)d_in[2];
    const float* bproj = (const float*)d_in[3];
    float* out = (float*)d_out;
    char* ws = (char*)d_ws;

    // workspace layout (bytes):
    const size_t off_xb    = 0;             // 33,554,432 x bf16 (obuf overlays)
    const size_t off_wqkv  = 33554432;      //  6,291,456
    const size_t off_wproj = 39845888;      //  2,097,152
    const size_t off_qk    = 41943040;      // 67,108,864 interleaved q/k (P overlays)
    const size_t off_vt    = 109051904;     // 33,554,432
    const size_t off_S     = 142606336;     // NZ * 8,388,608 bf16 logits chunk
    // adaptive chunk: largest NZ in {8,4,2,1} that fits
    int NZ = 0;
    for (int c = 8; c >= 1; c >>= 1)
        if (off_S + (size_t)c * 8388608 <= ws_size) { NZ = c; break; }
    if (NZ == 0) return;  // fail loudly via absmax check

    unsigned short* xb     = (unsigned short*)(ws + off_xb);
    unsigned short* wqkvb  = (unsigned short*)(ws + off_wqkv);
    unsigned short* wprojb = (unsigned short*)(ws + off_wproj);
    unsigned short* qkb    = (unsigned short*)(ws + off_qk);
    unsigned short* vtb    = (unsigned short*)(ws + off_vt);
    unsigned short* Sb     = (unsigned short*)(ws + off_S);
    unsigned short* obuf   = (unsigned short*)(ws + off_xb);  // overlay

    k_f2b<<<16384, 256, 0, stream>>>(x, xb, 4194304);
    k_f2b<<<3072, 256, 0, stream>>>(wqkv, wqkvb, 786432);
    k_f2b<<<1024, 256, 0, stream>>>(wproj, wprojb, 262144);

    k_gemm_qkv_qk<<<dim3(64, 16), 256, 0, stream>>>(xb, wqkvb, qkb);
    k_gemm_vt<<<dim3(4, 128), 256, 0, stream>>>(wqkvb + (size_t)2048 * 1024, xb, vtb);

    for (int z0 = 0; z0 < 8; z0 += NZ) {
        k_gemm_scores<<<dim3(8, 16, NZ), 256, 0, stream>>>(qkb, Sb, z0);
        k_softmax<<<NZ * 2048, 256, 0, stream>>>(Sb, qkb, z0);
        k_gemm_pv<<<dim3(4, 16, NZ), 256, 0, stream>>>(vtb, qkb, obuf, z0);
    }
    k_gemm_proj<<<dim3(64, 8), 256, 0, stream>>>(obuf, wprojb, bproj, out);
}

// Round 11
// 358.633 us; speedup vs baseline: 1.0438x; 1.0438x over previous
//
#include <hip/hip_runtime.h>

typedef __bf16 bf16x8_t __attribute__((ext_vector_type(8)));
typedef float f32x4_t __attribute__((ext_vector_type(4)));

#define AS1 __attribute__((address_space(1)))
#define AS3 __attribute__((address_space(3)))

__device__ __forceinline__ unsigned short f2b(float f) {
    unsigned u = __builtin_bit_cast(unsigned, f);
    u += 0x7fffu + ((u >> 16) & 1u);
    return (unsigned short)(u >> 16);
}
__device__ __forceinline__ float b2f(unsigned short s) {
    return __builtin_bit_cast(float, (unsigned)s << 16);
}

// ---------------------------------------------------------------------------
// fp32 -> bf16 convert, 4 elems/thread
// ---------------------------------------------------------------------------
__global__ __launch_bounds__(256) void k_f2b(const float* __restrict__ in,
                                             unsigned short* __restrict__ out,
                                             int n4) {
    int i = blockIdx.x * 256 + threadIdx.x;
    if (i >= n4) return;
    float4 v = reinterpret_cast<const float4*>(in)[i];
    ushort4 o;
    o.x = f2b(v.x); o.y = f2b(v.y); o.z = f2b(v.z); o.w = f2b(v.w);
    reinterpret_cast<ushort4*>(out)[i] = o;
}

// ---------------------------------------------------------------------------
// r9 structure + CORRECT 64B-row swizzle. C-tile 256(M) x 128(N), BK=32,
// 512 threads = 8 waves (4M x 2N), wave = 64x64 = 4x4 frags (acc 64 VGPR,
// 4 waves/SIMD). LDS 3 x 24KB = 72KB -> 2 blocks/CU, 16 waves/CU (r9's
// occupancy win: independent blocks fill barrier/vmcnt stalls; r9 = best
// qkv 86us even with 8-way conflicts; r10's 256-thread variant lost the
// wave count and regressed).
// Swizzle derivation (this time checked against slot algebra): frag read
// lane (fr,g) hits 16B-slot (addr>>4)&7 = 4*(fr&1) + (g ^ s(fr)). 2-to-1
// over 16 lanes (free, m136) requires s to cover {0..3} twice on even frs
// and twice on odd frs -> s(fr) = (fr>>1)&3. (r9: s=0 -> 8-way, 8.4M cy;
// r10: s=fr&3 -> 4-way, 6.3M cy. Both measured, both wrong.)
// Read byte-in-row: (g*16) ^ (((fr>>1)&3)<<4). Stage: linear LDS dest,
// global source col ((l&3)*16) ^ (((l>>3)&3)<<4)  [row = wave*16+(l>>2),
// (row>>1)&3 == (l>>3)&3]. Bijective per row; read returns unswizzled data.
// Schedule: counted-vmcnt 3-buffer loop; 3 loads/tile -> vmcnt(3); stage t+2
// after the barrier (buffer last read at t-1); wait BEFORE the barrier;
// never vmcnt(0) mid-loop.
// ---------------------------------------------------------------------------
#define STAGE(tt, bb) do {                                                     \
    char* dst_ = smem + (bb) * 24576;                                          \
    const size_t kof_ = (size_t)(tt) * 32;                                     \
    __builtin_amdgcn_global_load_lds((const AS1 void*)(pA0 + kof_),            \
        (AS3 void*)(dst_ + wave * 1024), 16, 0, 0);                            \
    __builtin_amdgcn_global_load_lds((const AS1 void*)(pA1 + kof_),            \
        (AS3 void*)(dst_ + 8192 + wave * 1024), 16, 0, 0);                     \
    __builtin_amdgcn_global_load_lds((const AS1 void*)(pB0 + kof_),            \
        (AS3 void*)(dst_ + 16384 + wave * 1024), 16, 0, 0);                    \
} while (0)

__device__ __forceinline__ void gemm_mainloop(
    const unsigned short* __restrict__ A, int lda,
    const unsigned short* __restrict__ B, int ldb,
    int K, char* smem, f32x4_t acc[4][4]) {
    const int tid = threadIdx.x;
    const int wave = tid >> 6, lane = tid & 63;
    const int wm = wave >> 1, wn = wave & 1;
    const int fr = lane & 15, g = lane >> 4;

    // staging: row = wave*16 + (lane>>2); source col pre-swizzled by
    // (((l>>3)&3)<<4) == ((row>>1)&3)<<4; LDS dest linear (lane*16).
    const int scolB = ((lane & 3) * 16) ^ (((lane >> 3) & 3) << 4);
    const unsigned short* pA0 = A + (size_t)(wave * 16 + (lane >> 2)) * lda + (scolB >> 1);
    const unsigned short* pA1 = pA0 + (size_t)128 * lda;
    const unsigned short* pB0 = B + (size_t)(wave * 16 + (lane >> 2)) * ldb + (scolB >> 1);

    // frag ds_read offsets: row*64 + ((g*16) ^ (((fr>>1)&3)<<4))
    const int rswz = (g * 16) ^ (((fr >> 1) & 3) << 4);
    int offA[4], offB[4];
#pragma unroll
    for (int mi = 0; mi < 4; ++mi)
        offA[mi] = (wm * 64 + mi * 16 + fr) * 64 + rswz;
#pragma unroll
    for (int ni = 0; ni < 4; ++ni)
        offB[ni] = 16384 + (wn * 64 + ni * 16 + fr) * 64 + rswz;

#pragma unroll
    for (int mi = 0; mi < 4; ++mi)
#pragma unroll
        for (int ni = 0; ni < 4; ++ni)
            acc[mi][ni] = (f32x4_t){0.f, 0.f, 0.f, 0.f};

    const int NT = K >> 5;   // K multiple of 64 -> NT >= 2

    STAGE(0, 0);
    STAGE(1, 1);

    int cb = 0;
    for (int t = 0; t < NT; ++t) {
        if (t + 1 < NT) asm volatile("s_waitcnt vmcnt(3)" ::: "memory");
        else            asm volatile("s_waitcnt vmcnt(0)" ::: "memory");
        asm volatile("s_barrier" ::: "memory");
        if (t + 2 < NT) {
            int sb = cb + 2; if (sb >= 3) sb -= 3;
            STAGE(t + 2, sb);   // safe: sb last read at t-1, readers passed barrier
        }
        const char* rb = smem + cb * 24576;
        bf16x8_t af[4], bfv[4];
#pragma unroll
        for (int mi = 0; mi < 4; ++mi)
            af[mi] = *reinterpret_cast<const bf16x8_t*>(rb + offA[mi]);
#pragma unroll
        for (int ni = 0; ni < 4; ++ni)
            bfv[ni] = *reinterpret_cast<const bf16x8_t*>(rb + offB[ni]);
        __builtin_amdgcn_s_setprio(1);
#pragma unroll
        for (int mi = 0; mi < 4; ++mi)
#pragma unroll
            for (int ni = 0; ni < 4; ++ni)
                acc[mi][ni] = __builtin_amdgcn_mfma_f32_16x16x32_bf16(
                    af[mi], bfv[ni], acc[mi][ni], 0, 0, 0);
        __builtin_amdgcn_s_setprio(0);
        cb = (cb + 1 == 3) ? 0 : cb + 1;
    }
}

// Epilogue: acc[mi][ni][j] -> row = tm + wm*64 + mi*16 + (lane>>4)*4 + j
//                            col = tn + wn*64 + ni*16 + (lane&15)
#define EPILOGUE_IDX                                            \
    const int lane = threadIdx.x & 63, wave = threadIdx.x >> 6; \
    const int e_r0 = (wave >> 1) * 64 + (lane >> 4) * 4;        \
    const int e_c0 = (wave & 1) * 64 + (lane & 15);

#define EPILOGUE_LOOP(...)                                      \
    _Pragma("unroll") for (int mi = 0; mi < 4; ++mi)            \
    _Pragma("unroll") for (int ni = 0; ni < 4; ++ni)            \
    _Pragma("unroll") for (int j = 0; j < 4; ++j) { __VA_ARGS__ }

// Interleaved q/k layout: per batch z (8 total), base elem z*4194304:
//   q_z[2048][1024] at +0, k_z[2048][1024] at +2097152.
// Softmax output P_z[2048][2048] bf16 later overlays exactly this region.

// ---------------------------------------------------------------------------
// QKV GEMM, Q/K half: M=16384 tokens, N=2048 (w_qkv rows 0..2047), K=1024
// ---------------------------------------------------------------------------
__global__ __launch_bounds__(512, 4) void k_gemm_qkv_qk(
    const unsigned short* __restrict__ x, const unsigned short* __restrict__ w,
    unsigned short* __restrict__ qk) {
    __shared__ __align__(16) char smem[73728];
    const size_t tm = (size_t)blockIdx.x * 256, tn = (size_t)blockIdx.y * 128;
    f32x4_t acc[4][4];
    gemm_mainloop(x + tm * 1024, 1024, w + tn * 1024, 1024, 1024, smem, acc);
    EPILOGUE_IDX
    EPILOGUE_LOOP(
        size_t m = tm + e_r0 + mi * 16 + j;
        size_t z = m >> 11;
        size_t nloc = m & 2047;
        int n = (int)tn + e_c0 + ni * 16;
        unsigned short v = f2b(acc[mi][ni][j]);
        size_t base = z * 4194304 + nloc * 1024;
        if (n < 1024) qk[base + n] = v;
        else          qk[base + 2097152 + (n - 1024)] = v;
    )
}

// ---------------------------------------------------------------------------
// QKV GEMM, V^T half (operands swapped): M=1024 (v-weight rows), N=16384
// tokens, K=1024.  vt[c][token] = v[token][c], coalesced stores.
// ---------------------------------------------------------------------------
__global__ __launch_bounds__(512, 4) void k_gemm_vt(
    const unsigned short* __restrict__ wv, const unsigned short* __restrict__ x,
    unsigned short* __restrict__ vt) {
    __shared__ __align__(16) char smem[73728];
    const size_t tm = (size_t)blockIdx.x * 256, tn = (size_t)blockIdx.y * 128;
    f32x4_t acc[4][4];
    gemm_mainloop(wv + tm * 1024, 1024, x + tn * 1024, 1024, 1024, smem, acc);
    EPILOGUE_IDX
    EPILOGUE_LOOP(
        size_t m = tm + e_r0 + mi * 16 + j;   // c
        size_t n = tn + e_c0 + ni * 16;       // token
        vt[m * 16384 + n] = f2b(acc[mi][ni][j]);
    )
}

// ---------------------------------------------------------------------------
// Scores: batch z = z0 + blockIdx.z; S[zlocal][nq][mk] = bf16((q·k)/32)
// ---------------------------------------------------------------------------
__global__ __launch_bounds__(512, 4) void k_gemm_scores(
    const unsigned short* __restrict__ qk, unsigned short* __restrict__ S, int z0) {
    __shared__ __align__(16) char smem[73728];
    const size_t z = z0 + blockIdx.z;
    const size_t tm = (size_t)blockIdx.x * 256, tn = (size_t)blockIdx.y * 128;
    const unsigned short* qz = qk + z * 4194304;
    const unsigned short* kz = qz + 2097152;
    f32x4_t acc[4][4];
    gemm_mainloop(qz + tm * 1024, 1024, kz + tn * 1024, 1024, 1024, smem, acc);
    EPILOGUE_IDX
    unsigned short* Sz = S + (size_t)blockIdx.z * 4194304;
    EPILOGUE_LOOP(
        size_t m = tm + e_r0 + mi * 16 + j;
        size_t n = tn + e_c0 + ni * 16;
        Sz[m * 2048 + n] = f2b(acc[mi][ni][j] * 0.03125f);
    )
}

// ---------------------------------------------------------------------------
// Row softmax: NZ*2048 rows x 2048, bf16 in -> bf16 out (P overlays q/k)
// One 16B vector (8 bf16) per thread.
// ---------------------------------------------------------------------------
__global__ __launch_bounds__(256) void k_softmax(const unsigned short* __restrict__ S,
                                                 unsigned short* __restrict__ qk,
                                                 int z0) {
    const size_t r = blockIdx.x;                 // row within chunk
    const int t = threadIdx.x, wv = t >> 6, ln = t & 63;
    const uint4 u = reinterpret_cast<const uint4*>(S + r * 2048)[t];
    float vals[8];
    vals[0] = b2f((unsigned short)(u.x & 0xffff)); vals[1] = b2f((unsigned short)(u.x >> 16));
    vals[2] = b2f((unsigned short)(u.y & 0xffff)); vals[3] = b2f((unsigned short)(u.y >> 16));
    vals[4] = b2f((unsigned short)(u.z & 0xffff)); vals[5] = b2f((unsigned short)(u.z >> 16));
    vals[6] = b2f((unsigned short)(u.w & 0xffff)); vals[7] = b2f((unsigned short)(u.w >> 16));

    float mx = vals[0];
#pragma unroll
    for (int i = 1; i < 8; ++i) mx = fmaxf(mx, vals[i]);
#pragma unroll
    for (int i = 32; i > 0; i >>= 1) mx = fmaxf(mx, __shfl_xor(mx, i, 64));
    __shared__ float red[8];
    if (ln == 0) red[wv] = mx;
    __syncthreads();
    mx = fmaxf(fmaxf(red[0], red[1]), fmaxf(red[2], red[3]));

    float ex[8], s = 0.f;
#pragma unroll
    for (int i = 0; i < 8; ++i) { ex[i] = __expf(vals[i] - mx); s += ex[i]; }
#pragma unroll
    for (int i = 32; i > 0; i >>= 1) s += __shfl_xor(s, i, 64);
    if (ln == 0) red[4 + wv] = s;
    __syncthreads();
    s = (red[4] + red[5]) + (red[6] + red[7]);
    float inv = 1.0f / s;

    uint4 o;
    o.x = (unsigned)f2b(ex[0] * inv) | ((unsigned)f2b(ex[1] * inv) << 16);
    o.y = (unsigned)f2b(ex[2] * inv) | ((unsigned)f2b(ex[3] * inv) << 16);
    o.z = (unsigned)f2b(ex[4] * inv) | ((unsigned)f2b(ex[5] * inv) << 16);
    o.w = (unsigned)f2b(ex[6] * inv) | ((unsigned)f2b(ex[7] * inv) << 16);

    const size_t zg = z0 + (r >> 11), nloc = r & 2047;
    reinterpret_cast<uint4*>(qk + zg * 4194304 + nloc * 2048)[t] = o;
}

// ---------------------------------------------------------------------------
// PV as O^T: batch z = z0+blockIdx.z, O^T[c][n] = sum_m vt[c][m] * P[n][m]
// M=1024 (c), N=2048 (n), K=2048.  Stores apply the swapaxes-reshape
// scramble o2[2c + (n>>10)][n&1023] = o[n][c] -> coalesced in n.
// ---------------------------------------------------------------------------
__global__ __launch_bounds__(512, 4) void k_gemm_pv(
    const unsigned short* __restrict__ vt, const unsigned short* __restrict__ qk,
    unsigned short* __restrict__ ob, int z0) {
    __shared__ __align__(16) char smem[73728];
    const size_t z = z0 + blockIdx.z;
    const size_t tm = (size_t)blockIdx.x * 256, tn = (size_t)blockIdx.y * 128;
    const unsigned short* P = qk + z * 4194304;
    f32x4_t acc[4][4];
    gemm_mainloop(vt + tm * 16384 + z * 2048, 16384,
                  P + tn * 2048, 2048, 2048, smem, acc);
    EPILOGUE_IDX
    unsigned short* oz = ob + z * 2097152;
    EPILOGUE_LOOP(
        size_t m = tm + e_r0 + mi * 16 + j;   // c
        size_t n = tn + e_c0 + ni * 16;       // token n within batch
        oz[(2 * m + (n >> 10)) * 1024 + (n & 1023)] = f2b(acc[mi][ni][j]);
    )
}

// ---------------------------------------------------------------------------
// Proj: out[m][d] = sum_j o2[m][j] * w_proj[d][j] + b_proj[d], fp32 out
// M=16384, N=1024, K=1024
// ---------------------------------------------------------------------------
__global__ __launch_bounds__(512, 4) void k_gemm_proj(
    const unsigned short* __restrict__ o2, const unsigned short* __restrict__ w,
    const float* __restrict__ bias, float* __restrict__ out) {
    __shared__ __align__(16) char smem[73728];
    const size_t tm = (size_t)blockIdx.x * 256, tn = (size_t)blockIdx.y * 128;
    f32x4_t acc[4][4];
    gemm_mainloop(o2 + tm * 1024, 1024, w + tn * 1024, 1024, 1024, smem, acc);
    EPILOGUE_IDX
    EPILOGUE_LOOP(
        size_t m = tm + e_r0 + mi * 16 + j;
        size_t n = tn + e_c0 + ni * 16;
        out[m * 1024 + n] = acc[mi][ni][j] + bias[n];
    )
}

// ---------------------------------------------------------------------------
extern "C" void kernel_launch(void* const* d_in, const int* in_sizes, int n_in,
                              void* d_out, int out_size, void* d_ws, size_t ws_size,
                              hipStream_t stream) {
    const float* x     = (const float*)d_in[0];
    const float* wqkv  = (const float*)d_in[1];
    const float* wproj = (const float*)d_in[2];
    const float* bproj = (const float*)d_in[3];
    float* out = (float*)d_out;
    char* ws = (char*)d_ws;

    // workspace layout (bytes):
    const size_t off_xb    = 0;             // 33,554,432 x bf16 (obuf overlays)
    const size_t off_wqkv  = 33554432;      //  6,291,456
    const size_t off_wproj = 39845888;      //  2,097,152
    const size_t off_qk    = 41943040;      // 67,108,864 interleaved q/k (P overlays)
    const size_t off_vt    = 109051904;     // 33,554,432
    const size_t off_S     = 142606336;     // NZ * 8,388,608 bf16 logits chunk
    // adaptive chunk: largest NZ in {8,4,2,1} that fits
    int NZ = 0;
    for (int c = 8; c >= 1; c >>= 1)
        if (off_S + (size_t)c * 8388608 <= ws_size) { NZ = c; break; }
    if (NZ == 0) return;  // fail loudly via absmax check

    unsigned short* xb     = (unsigned short*)(ws + off_xb);
    unsigned short* wqkvb  = (unsigned short*)(ws + off_wqkv);
    unsigned short* wprojb = (unsigned short*)(ws + off_wproj);
    unsigned short* qkb    = (unsigned short*)(ws + off_qk);
    unsigned short* vtb    = (unsigned short*)(ws + off_vt);
    unsigned short* Sb     = (unsigned short*)(ws + off_S);
    unsigned short* obuf   = (unsigned short*)(ws + off_xb);  // overlay

    k_f2b<<<16384, 256, 0, stream>>>(x, xb, 4194304);
    k_f2b<<<3072, 256, 0, stream>>>(wqkv, wqkvb, 786432);
    k_f2b<<<1024, 256, 0, stream>>>(wproj, wprojb, 262144);

    k_gemm_qkv_qk<<<dim3(64, 16), 512, 0, stream>>>(xb, wqkvb, qkb);
    k_gemm_vt<<<dim3(4, 128), 512, 0, stream>>>(wqkvb + (size_t)2048 * 1024, xb, vtb);

    for (int z0 = 0; z0 < 8; z0 += NZ) {
        k_gemm_scores<<<dim3(8, 16, NZ), 512, 0, stream>>>(qkb, Sb, z0);
        k_softmax<<<NZ * 2048, 256, 0, stream>>>(Sb, qkb, z0);
        k_gemm_pv<<<dim3(4, 16, NZ), 512, 0, stream>>>(vtb, qkb, obuf, z0);
    }
    k_gemm_proj<<<dim3(64, 8), 512, 0, stream>>>(obuf, wprojb, bproj, out);
}

// Round 12
// 341.134 us; speedup vs baseline: 1.0973x; 1.0513x over previous
//
#include <hip/hip_runtime.h>

typedef __bf16 bf16x8_t __attribute__((ext_vector_type(8)));
typedef float f32x4_t __attribute__((ext_vector_type(4)));

#define AS1 __attribute__((address_space(1)))
#define AS3 __attribute__((address_space(3)))

__device__ __forceinline__ unsigned short f2b(float f) {
    unsigned u = __builtin_bit_cast(unsigned, f);
    u += 0x7fffu + ((u >> 16) & 1u);
    return (unsigned short)(u >> 16);
}
__device__ __forceinline__ float b2f(unsigned short s) {
    return __builtin_bit_cast(float, (unsigned)s << 16);
}

// ---------------------------------------------------------------------------
// fp32 -> bf16 convert, 4 elems/thread
// ---------------------------------------------------------------------------
__global__ __launch_bounds__(256) void k_f2b(const float* __restrict__ in,
                                             unsigned short* __restrict__ out,
                                             int n4) {
    int i = blockIdx.x * 256 + threadIdx.x;
    if (i >= n4) return;
    float4 v = reinterpret_cast<const float4*>(in)[i];
    ushort4 o;
    o.x = f2b(v.x); o.y = f2b(v.y); o.z = f2b(v.z); o.w = f2b(v.w);
    reinterpret_cast<ushort4*>(out)[i] = o;
}

// ===========================================================================
// ENGINE A (r11, measured qkv 85us, 0 conflicts): 256(M) x 128(N), BK=32,
// 512 threads = 8 waves (4M x 2N), wave 64x64 = 4x4 frags. LDS 3 x 24KB =
// 72KB -> 2 blocks/CU (16 waves/CU fill barrier/vmcnt stalls). Counted
// vmcnt(3) 3-buffer loop; stage t+2 after barrier; never vmcnt(0) mid-loop.
// 64B-row swizzle s(fr)=(fr>>1)&3: read (g*16)^(((fr>>1)&3)<<4); staging
// pre-swizzles global col ((l&3)*16)^(((l>>3)&3)<<4), linear LDS dest.
// Used for: qkv_qk, vt (tall-skinny GEMMs where per-CU stall dominated).
// ===========================================================================
#define STAGE3(tt, bb) do {                                                    \
    char* dst_ = smem + (bb) * 24576;                                          \
    const size_t kof_ = (size_t)(tt) * 32;                                     \
    __builtin_amdgcn_global_load_lds((const AS1 void*)(pA0 + kof_),            \
        (AS3 void*)(dst_ + wave * 1024), 16, 0, 0);                            \
    __builtin_amdgcn_global_load_lds((const AS1 void*)(pA1 + kof_),            \
        (AS3 void*)(dst_ + 8192 + wave * 1024), 16, 0, 0);                     \
    __builtin_amdgcn_global_load_lds((const AS1 void*)(pB0 + kof_),            \
        (AS3 void*)(dst_ + 16384 + wave * 1024), 16, 0, 0);                    \
} while (0)

__device__ __forceinline__ void gemm_ml_128(
    const unsigned short* __restrict__ A, int lda,
    const unsigned short* __restrict__ B, int ldb,
    int K, char* smem, f32x4_t acc[4][4]) {
    const int tid = threadIdx.x;
    const int wave = tid >> 6, lane = tid & 63;
    const int wm = wave >> 1, wn = wave & 1;
    const int fr = lane & 15, g = lane >> 4;

    const int scolB = ((lane & 3) * 16) ^ (((lane >> 3) & 3) << 4);
    const unsigned short* pA0 = A + (size_t)(wave * 16 + (lane >> 2)) * lda + (scolB >> 1);
    const unsigned short* pA1 = pA0 + (size_t)128 * lda;
    const unsigned short* pB0 = B + (size_t)(wave * 16 + (lane >> 2)) * ldb + (scolB >> 1);

    const int rswz = (g * 16) ^ (((fr >> 1) & 3) << 4);
    int offA[4], offB[4];
#pragma unroll
    for (int mi = 0; mi < 4; ++mi)
        offA[mi] = (wm * 64 + mi * 16 + fr) * 64 + rswz;
#pragma unroll
    for (int ni = 0; ni < 4; ++ni)
        offB[ni] = 16384 + (wn * 64 + ni * 16 + fr) * 64 + rswz;

#pragma unroll
    for (int mi = 0; mi < 4; ++mi)
#pragma unroll
        for (int ni = 0; ni < 4; ++ni)
            acc[mi][ni] = (f32x4_t){0.f, 0.f, 0.f, 0.f};

    const int NT = K >> 5;

    STAGE3(0, 0);
    STAGE3(1, 1);

    int cb = 0;
    for (int t = 0; t < NT; ++t) {
        if (t + 1 < NT) asm volatile("s_waitcnt vmcnt(3)" ::: "memory");
        else            asm volatile("s_waitcnt vmcnt(0)" ::: "memory");
        asm volatile("s_barrier" ::: "memory");
        if (t + 2 < NT) {
            int sb = cb + 2; if (sb >= 3) sb -= 3;
            STAGE3(t + 2, sb);
        }
        const char* rb = smem + cb * 24576;
        bf16x8_t af[4], bfv[4];
#pragma unroll
        for (int mi = 0; mi < 4; ++mi)
            af[mi] = *reinterpret_cast<const bf16x8_t*>(rb + offA[mi]);
#pragma unroll
        for (int ni = 0; ni < 4; ++ni)
            bfv[ni] = *reinterpret_cast<const bf16x8_t*>(rb + offB[ni]);
        __builtin_amdgcn_s_setprio(1);
#pragma unroll
        for (int mi = 0; mi < 4; ++mi)
#pragma unroll
            for (int ni = 0; ni < 4; ++ni)
                acc[mi][ni] = __builtin_amdgcn_mfma_f32_16x16x32_bf16(
                    af[mi], bfv[ni], acc[mi][ni], 0, 0, 0);
        __builtin_amdgcn_s_setprio(0);
        cb = (cb + 1 == 3) ? 0 : cb + 1;
    }
}

#define E128_IDX                                                \
    const int lane = threadIdx.x & 63, wave = threadIdx.x >> 6; \
    const int e_r0 = (wave >> 1) * 64 + (lane >> 4) * 4;        \
    const int e_c0 = (wave & 1) * 64 + (lane & 15);

#define E128_LOOP(...)                                          \
    _Pragma("unroll") for (int mi = 0; mi < 4; ++mi)            \
    _Pragma("unroll") for (int ni = 0; ni < 4; ++ni)            \
    _Pragma("unroll") for (int j = 0; j < 4; ++j) { __VA_ARGS__ }

// ===========================================================================
// ENGINE B (r8, best total; 0 conflicts): 256x256, BK=64, 512 threads =
// 8 waves; per K-tile 2 phases x 32 MFMA over 128x128 quadrants; 2 LDS
// buffers x 64KB = 128KB (1 block/CU). Counted waits vmcnt(2)/vmcnt(4)
// BEFORE their barrier; stage after barrier into buf^1. 128B-row swizzle
// ((row&7)<<4), pre-swizzled global source, linear LDS dest.
// Used for: scores, pv, proj (square-ish GEMMs where operand traffic
// dominates; 256^2 tile = minimal (1/BM+1/BN)).
// ===========================================================================
#define STA(h, i)                                                              \
    __builtin_amdgcn_global_load_lds(                                         \
        (const AS1 void*)(pA + kof + (size_t)((h) * 128 + (i) * 8) * lda),    \
        (AS3 void*)(wb + (h) * 16384 + wave * 2048 + (i) * 1024), 16, 0, 0)
#define STB(h, i)                                                              \
    __builtin_amdgcn_global_load_lds(                                         \
        (const AS1 void*)(pB + kof + (size_t)((h) * 128 + (i) * 8) * ldb),    \
        (AS3 void*)(wb + 32768 + (h) * 16384 + wave * 2048 + (i) * 1024), 16, 0, 0)

#define READ_A(qm)                                                             \
    _Pragma("unroll") for (int mi = 0; mi < 4; ++mi)                           \
        _Pragma("unroll") for (int ks = 0; ks < 2; ++ks)                       \
            af[mi][ks] = *reinterpret_cast<const bf16x8_t*>(rb + offA[qm][mi][ks]);
#define READ_B(qn)                                                             \
    _Pragma("unroll") for (int ni = 0; ni < 2; ++ni)                           \
        _Pragma("unroll") for (int ks = 0; ks < 2; ++ks)                       \
            bf[qn][ni][ks] = *reinterpret_cast<const bf16x8_t*>(rb + offB[qn][ni][ks]);

#define MFMA_QUAD(qm, qn)                                                      \
    __builtin_amdgcn_s_setprio(1);                                             \
    _Pragma("unroll") for (int mi = 0; mi < 4; ++mi)                           \
        _Pragma("unroll") for (int ni = 0; ni < 2; ++ni) {                     \
            acc[qm][qn][mi][ni] = __builtin_amdgcn_mfma_f32_16x16x32_bf16(     \
                af[mi][0], bf[qn][ni][0], acc[qm][qn][mi][ni], 0, 0, 0);       \
            acc[qm][qn][mi][ni] = __builtin_amdgcn_mfma_f32_16x16x32_bf16(     \
                af[mi][1], bf[qn][ni][1], acc[qm][qn][mi][ni], 0, 0, 0);       \
        }                                                                      \
    __builtin_amdgcn_s_setprio(0);

template <bool LAST>
__device__ __forceinline__ void tile_step(
    const char* rb, char* wb, size_t kof,
    const unsigned short* pA, const unsigned short* pB, int lda, int ldb,
    int wave, const int offA[2][4][2], const int offB[2][2][2],
    f32x4_t acc[2][2][4][2]) {
    bf16x8_t af[4][2], bf[2][2][2];
    // ---- PhA: quadrants (0,0),(0,1); needs A0,B0,B1 of tile t
    asm volatile("s_waitcnt vmcnt(2)" ::: "memory");
    asm volatile("s_barrier" ::: "memory");
    if constexpr (!LAST) { STA(0, 0); STA(0, 1); STB(0, 0); STB(0, 1); }
    READ_A(0); READ_B(0); READ_B(1);
    MFMA_QUAD(0, 0);
    MFMA_QUAD(0, 1);
    // ---- PhB: quadrants (1,1),(1,0); needs A1 of tile t
    if constexpr (LAST) asm volatile("s_waitcnt vmcnt(0)" ::: "memory");
    else                asm volatile("s_waitcnt vmcnt(4)" ::: "memory");
    asm volatile("s_barrier" ::: "memory");
    if constexpr (!LAST) { STB(1, 0); STB(1, 1); STA(1, 0); STA(1, 1); }
    READ_A(1);
    MFMA_QUAD(1, 1);
    MFMA_QUAD(1, 0);
}

__device__ __forceinline__ void gemm_ml_256(
    const unsigned short* __restrict__ A, int lda,
    const unsigned short* __restrict__ B, int ldb,
    int K, char* smem, f32x4_t acc[2][2][4][2]) {
    const int tid = threadIdx.x;
    const int wave = tid >> 6, lane = tid & 63;
    const int wsm = (wave >> 2) & 1, wsn = wave & 3;
    const int fr = lane & 15, g = lane >> 4;
    const int srow8 = lane >> 3;
    const int scolB = ((lane & 7) * 16) ^ (srow8 << 4);

    const unsigned short* pA = A + (size_t)(wave * 16 + srow8) * lda + (scolB >> 1);
    const unsigned short* pB = B + (size_t)(wave * 16 + srow8) * ldb + (scolB >> 1);

    int offA[2][4][2], offB[2][2][2];
#pragma unroll
    for (int qm = 0; qm < 2; ++qm)
#pragma unroll
        for (int mi = 0; mi < 4; ++mi)
#pragma unroll
            for (int ks = 0; ks < 2; ++ks)
                offA[qm][mi][ks] = qm * 16384 + (wsm * 64 + mi * 16 + fr) * 128 +
                                   ((ks * 64 + g * 16) ^ ((fr & 7) << 4));
#pragma unroll
    for (int qn = 0; qn < 2; ++qn)
#pragma unroll
        for (int ni = 0; ni < 2; ++ni)
#pragma unroll
            for (int ks = 0; ks < 2; ++ks)
                offB[qn][ni][ks] = 32768 + qn * 16384 + (wsn * 32 + ni * 16 + fr) * 128 +
                                   ((ks * 64 + g * 16) ^ ((fr & 7) << 4));

#pragma unroll
    for (int qm = 0; qm < 2; ++qm)
#pragma unroll
        for (int qn = 0; qn < 2; ++qn)
#pragma unroll
            for (int mi = 0; mi < 4; ++mi)
#pragma unroll
                for (int ni = 0; ni < 2; ++ni)
                    acc[qm][qn][mi][ni] = (f32x4_t){0.f, 0.f, 0.f, 0.f};

    const int NT = K >> 6;

    // prologue: stage tile 0 into buf0 in queue order A0, B0, B1, A1
    {
        char* wb = smem;
        const size_t kof = 0;
        STA(0, 0); STA(0, 1);
        STB(0, 0); STB(0, 1);
        STB(1, 0); STB(1, 1);
        STA(1, 0); STA(1, 1);
    }

    for (int t = 0; t < NT - 1; ++t) {
        const char* rb = smem + (size_t)(t & 1) * 65536;
        char* wb = smem + (size_t)((t & 1) ^ 1) * 65536;
        tile_step<false>(rb, wb, (size_t)(t + 1) * 64, pA, pB, lda, ldb,
                         wave, offA, offB, acc);
    }
    {
        const char* rb = smem + (size_t)((NT - 1) & 1) * 65536;
        tile_step<true>(rb, smem, 0, pA, pB, lda, ldb, wave, offA, offB, acc);
    }
}

#define E256_IDX                                                \
    const int lane = threadIdx.x & 63, wave = threadIdx.x >> 6; \
    const int e_r0 = ((wave >> 2) & 1) * 64 + (lane >> 4) * 4;  \
    const int e_c0 = (wave & 3) * 32 + (lane & 15);

#define E256_LOOP(...)                                          \
    _Pragma("unroll") for (int qm = 0; qm < 2; ++qm)            \
    _Pragma("unroll") for (int qn = 0; qn < 2; ++qn)            \
    _Pragma("unroll") for (int mi = 0; mi < 4; ++mi)            \
    _Pragma("unroll") for (int ni = 0; ni < 2; ++ni)            \
    _Pragma("unroll") for (int j = 0; j < 4; ++j) { __VA_ARGS__ }

// Interleaved q/k layout: per batch z (8 total), base elem z*4194304:
//   q_z[2048][1024] at +0, k_z[2048][1024] at +2097152.
// Softmax output P_z[2048][2048] bf16 later overlays exactly this region.

// ---------------------------------------------------------------------------
// QKV GEMM, Q/K half (ENGINE A): M=16384, N=2048, K=1024
// ---------------------------------------------------------------------------
__global__ __launch_bounds__(512, 4) void k_gemm_qkv_qk(
    const unsigned short* __restrict__ x, const unsigned short* __restrict__ w,
    unsigned short* __restrict__ qk) {
    __shared__ __align__(16) char smem[73728];
    const size_t tm = (size_t)blockIdx.x * 256, tn = (size_t)blockIdx.y * 128;
    f32x4_t acc[4][4];
    gemm_ml_128(x + tm * 1024, 1024, w + tn * 1024, 1024, 1024, smem, acc);
    E128_IDX
    E128_LOOP(
        size_t m = tm + e_r0 + mi * 16 + j;
        size_t z = m >> 11;
        size_t nloc = m & 2047;
        int n = (int)tn + e_c0 + ni * 16;
        unsigned short v = f2b(acc[mi][ni][j]);
        size_t base = z * 4194304 + nloc * 1024;
        if (n < 1024) qk[base + n] = v;
        else          qk[base + 2097152 + (n - 1024)] = v;
    )
}

// ---------------------------------------------------------------------------
// QKV GEMM, V^T half (ENGINE A, operands swapped): M=1024, N=16384, K=1024
// vt[c][token] = v[token][c], coalesced stores.
// ---------------------------------------------------------------------------
__global__ __launch_bounds__(512, 4) void k_gemm_vt(
    const unsigned short* __restrict__ wv, const unsigned short* __restrict__ x,
    unsigned short* __restrict__ vt) {
    __shared__ __align__(16) char smem[73728];
    const size_t tm = (size_t)blockIdx.x * 256, tn = (size_t)blockIdx.y * 128;
    f32x4_t acc[4][4];
    gemm_ml_128(wv + tm * 1024, 1024, x + tn * 1024, 1024, 1024, smem, acc);
    E128_IDX
    E128_LOOP(
        size_t m = tm + e_r0 + mi * 16 + j;   // c
        size_t n = tn + e_c0 + ni * 16;       // token
        vt[m * 16384 + n] = f2b(acc[mi][ni][j]);
    )
}

// ---------------------------------------------------------------------------
// Scores (ENGINE B): batch z = z0 + blockIdx.z; S = bf16((q·k)/32)
// ---------------------------------------------------------------------------
__global__ __launch_bounds__(512, 2) void k_gemm_scores(
    const unsigned short* __restrict__ qk, unsigned short* __restrict__ S, int z0) {
    __shared__ __align__(16) char smem[131072];
    const size_t z = z0 + blockIdx.z;
    const size_t tm = (size_t)blockIdx.x * 256, tn = (size_t)blockIdx.y * 256;
    const unsigned short* qz = qk + z * 4194304;
    const unsigned short* kz = qz + 2097152;
    f32x4_t acc[2][2][4][2];
    gemm_ml_256(qz + tm * 1024, 1024, kz + tn * 1024, 1024, 1024, smem, acc);
    E256_IDX
    unsigned short* Sz = S + (size_t)blockIdx.z * 4194304;
    E256_LOOP(
        size_t m = tm + qm * 128 + e_r0 + mi * 16 + j;
        size_t n = tn + qn * 128 + e_c0 + ni * 16;
        Sz[m * 2048 + n] = f2b(acc[qm][qn][mi][ni][j] * 0.03125f);
    )
}

// ---------------------------------------------------------------------------
// Row softmax: NZ*2048 rows x 2048, bf16 in -> bf16 out (P overlays q/k)
// ---------------------------------------------------------------------------
__global__ __launch_bounds__(256) void k_softmax(const unsigned short* __restrict__ S,
                                                 unsigned short* __restrict__ qk,
                                                 int z0) {
    const size_t r = blockIdx.x;
    const int t = threadIdx.x, wv = t >> 6, ln = t & 63;
    const uint4 u = reinterpret_cast<const uint4*>(S + r * 2048)[t];
    float vals[8];
    vals[0] = b2f((unsigned short)(u.x & 0xffff)); vals[1] = b2f((unsigned short)(u.x >> 16));
    vals[2] = b2f((unsigned short)(u.y & 0xffff)); vals[3] = b2f((unsigned short)(u.y >> 16));
    vals[4] = b2f((unsigned short)(u.z & 0xffff)); vals[5] = b2f((unsigned short)(u.z >> 16));
    vals[6] = b2f((unsigned short)(u.w & 0xffff)); vals[7] = b2f((unsigned short)(u.w >> 16));

    float mx = vals[0];
#pragma unroll
    for (int i = 1; i < 8; ++i) mx = fmaxf(mx, vals[i]);
#pragma unroll
    for (int i = 32; i > 0; i >>= 1) mx = fmaxf(mx, __shfl_xor(mx, i, 64));
    __shared__ float red[8];
    if (ln == 0) red[wv] = mx;
    __syncthreads();
    mx = fmaxf(fmaxf(red[0], red[1]), fmaxf(red[2], red[3]));

    float ex[8], s = 0.f;
#pragma unroll
    for (int i = 0; i < 8; ++i) { ex[i] = __expf(vals[i] - mx); s += ex[i]; }
#pragma unroll
    for (int i = 32; i > 0; i >>= 1) s += __shfl_xor(s, i, 64);
    if (ln == 0) red[4 + wv] = s;
    __syncthreads();
    s = (red[4] + red[5]) + (red[6] + red[7]);
    float inv = 1.0f / s;

    uint4 o;
    o.x = (unsigned)f2b(ex[0] * inv) | ((unsigned)f2b(ex[1] * inv) << 16);
    o.y = (unsigned)f2b(ex[2] * inv) | ((unsigned)f2b(ex[3] * inv) << 16);
    o.z = (unsigned)f2b(ex[4] * inv) | ((unsigned)f2b(ex[5] * inv) << 16);
    o.w = (unsigned)f2b(ex[6] * inv) | ((unsigned)f2b(ex[7] * inv) << 16);

    const size_t zg = z0 + (r >> 11), nloc = r & 2047;
    reinterpret_cast<uint4*>(qk + zg * 4194304 + nloc * 2048)[t] = o;
}

// ---------------------------------------------------------------------------
// PV as O^T (ENGINE B): O^T[c][n] = sum_m vt[c][m] * P[n][m]
// M=1024 (c), N=2048 (n), K=2048; scrambled coalesced stores.
// ---------------------------------------------------------------------------
__global__ __launch_bounds__(512, 2) void k_gemm_pv(
    const unsigned short* __restrict__ vt, const unsigned short* __restrict__ qk,
    unsigned short* __restrict__ ob, int z0) {
    __shared__ __align__(16) char smem[131072];
    const size_t z = z0 + blockIdx.z;
    const size_t tm = (size_t)blockIdx.x * 256, tn = (size_t)blockIdx.y * 256;
    const unsigned short* P = qk + z * 4194304;
    f32x4_t acc[2][2][4][2];
    gemm_ml_256(vt + tm * 16384 + z * 2048, 16384,
                P + tn * 2048, 2048, 2048, smem, acc);
    E256_IDX
    unsigned short* oz = ob + z * 2097152;
    E256_LOOP(
        size_t m = tm + qm * 128 + e_r0 + mi * 16 + j;   // c
        size_t n = tn + qn * 128 + e_c0 + ni * 16;       // token n within batch
        oz[(2 * m + (n >> 10)) * 1024 + (n & 1023)] = f2b(acc[qm][qn][mi][ni][j]);
    )
}

// ---------------------------------------------------------------------------
// Proj (ENGINE B): out[m][d] = sum_j o2[m][j] * w_proj[d][j] + b_proj[d]
// M=16384, N=1024, K=1024, fp32 out
// ---------------------------------------------------------------------------
__global__ __launch_bounds__(512, 2) void k_gemm_proj(
    const unsigned short* __restrict__ o2, const unsigned short* __restrict__ w,
    const float* __restrict__ bias, float* __restrict__ out) {
    __shared__ __align__(16) char smem[131072];
    const size_t tm = (size_t)blockIdx.x * 256, tn = (size_t)blockIdx.y * 256;
    f32x4_t acc[2][2][4][2];
    gemm_ml_256(o2 + tm * 1024, 1024, w + tn * 1024, 1024, 1024, smem, acc);
    E256_IDX
    E256_LOOP(
        size_t m = tm + qm * 128 + e_r0 + mi * 16 + j;
        size_t n = tn + qn * 128 + e_c0 + ni * 16;
        out[m * 1024 + n] = acc[qm][qn][mi][ni][j] + bias[n];
    )
}

// ---------------------------------------------------------------------------
extern "C" void kernel_launch(void* const* d_in, const int* in_sizes, int n_in,
                              void* d_out, int out_size, void* d_ws, size_t ws_size,
                              hipStream_t stream) {
    const float* x     = (const float*)d_in[0];
    const float* wqkv  = (const float*)d_in[1];
    const float* wproj = (const float*)d_in[2];
    const float* bproj = (const float*)d_in[3];
    float* out = (float*)d_out;
    char* ws = (char*)d_ws;

    // workspace layout (bytes):
    const size_t off_xb    = 0;             // 33,554,432 x bf16 (obuf overlays)
    const size_t off_wqkv  = 33554432;      //  6,291,456
    const size_t off_wproj = 39845888;      //  2,097,152
    const size_t off_qk    = 41943040;      // 67,108,864 interleaved q/k (P overlays)
    const size_t off_vt    = 109051904;     // 33,554,432
    const size_t off_S     = 142606336;     // NZ * 8,388,608 bf16 logits chunk
    // adaptive chunk: largest NZ in {8,4,2,1} that fits
    int NZ = 0;
    for (int c = 8; c >= 1; c >>= 1)
        if (off_S + (size_t)c * 8388608 <= ws_size) { NZ = c; break; }
    if (NZ == 0) return;  // fail loudly via absmax check

    unsigned short* xb     = (unsigned short*)(ws + off_xb);
    unsigned short* wqkvb  = (unsigned short*)(ws + off_wqkv);
    unsigned short* wprojb = (unsigned short*)(ws + off_wproj);
    unsigned short* qkb    = (unsigned short*)(ws + off_qk);
    unsigned short* vtb    = (unsigned short*)(ws + off_vt);
    unsigned short* Sb     = (unsigned short*)(ws + off_S);
    unsigned short* obuf   = (unsigned short*)(ws + off_xb);  // overlay

    k_f2b<<<16384, 256, 0, stream>>>(x, xb, 4194304);
    k_f2b<<<3072, 256, 0, stream>>>(wqkv, wqkvb, 786432);
    k_f2b<<<1024, 256, 0, stream>>>(wproj, wprojb, 262144);

    k_gemm_qkv_qk<<<dim3(64, 16), 512, 0, stream>>>(xb, wqkvb, qkb);
    k_gemm_vt<<<dim3(4, 128), 512, 0, stream>>>(wqkvb + (size_t)2048 * 1024, xb, vtb);

    for (int z0 = 0; z0 < 8; z0 += NZ) {
        k_gemm_scores<<<dim3(8, 8, NZ), 512, 0, stream>>>(qkb, Sb, z0);
        k_softmax<<<NZ * 2048, 256, 0, stream>>>(Sb, qkb, z0);
        k_gemm_pv<<<dim3(4, 8, NZ), 512, 0, stream>>>(vtb, qkb, obuf, z0);
    }
    k_gemm_proj<<<dim3(64, 4), 512, 0, stream>>>(obuf, wprojb, bproj, out);
}

// Round 13
// 335.782 us; speedup vs baseline: 1.1148x; 1.0159x over previous
//
#include <hip/hip_runtime.h>

typedef __bf16 bf16x8_t __attribute__((ext_vector_type(8)));
typedef float f32x4_t __attribute__((ext_vector_type(4)));

#define AS1 __attribute__((address_space(1)))
#define AS3 __attribute__((address_space(3)))

__device__ __forceinline__ unsigned short f2b(float f) {
    unsigned u = __builtin_bit_cast(unsigned, f);
    u += 0x7fffu + ((u >> 16) & 1u);
    return (unsigned short)(u >> 16);
}
__device__ __forceinline__ float b2f(unsigned short s) {
    return __builtin_bit_cast(float, (unsigned)s << 16);
}

// ---------------------------------------------------------------------------
// fp32 -> bf16 convert, 4 elems/thread
// ---------------------------------------------------------------------------
__global__ __launch_bounds__(256) void k_f2b(const float* __restrict__ in,
                                             unsigned short* __restrict__ out,
                                             int n4) {
    int i = blockIdx.x * 256 + threadIdx.x;
    if (i >= n4) return;
    float4 v = reinterpret_cast<const float4*>(in)[i];
    ushort4 o;
    o.x = f2b(v.x); o.y = f2b(v.y); o.z = f2b(v.z); o.w = f2b(v.w);
    reinterpret_cast<ushort4*>(out)[i] = o;
}

// ===========================================================================
// ENGINE A (r11/r12, measured qkv 85us, 0 conflicts): 256(M) x 128(N), BK=32,
// 512 threads = 8 waves (4M x 2N), wave 64x64 = 4x4 frags. LDS 3 x 24KB =
// 72KB -> 2 blocks/CU. Counted vmcnt(3) 3-buffer loop. 64B-row swizzle
// s(fr)=(fr>>1)&3. Used ONLY for qkv_qk (L2-resident B panel -> the extra
// tile traffic of the smaller tile is cache-absorbed; 2 blocks/CU fills
// stalls). vt measured WORSE here (r12: +26us) -> vt stays on Engine B.
// ===========================================================================
#define STAGE3(tt, bb) do {                                                    \
    char* dst_ = smem + (bb) * 24576;                                          \
    const size_t kof_ = (size_t)(tt) * 32;                                     \
    __builtin_amdgcn_global_load_lds((const AS1 void*)(pA0 + kof_),            \
        (AS3 void*)(dst_ + wave * 1024), 16, 0, 0);                            \
    __builtin_amdgcn_global_load_lds((const AS1 void*)(pA1 + kof_),            \
        (AS3 void*)(dst_ + 8192 + wave * 1024), 16, 0, 0);                     \
    __builtin_amdgcn_global_load_lds((const AS1 void*)(pB0 + kof_),            \
        (AS3 void*)(dst_ + 16384 + wave * 1024), 16, 0, 0);                    \
} while (0)

__device__ __forceinline__ void gemm_ml_128(
    const unsigned short* __restrict__ A, int lda,
    const unsigned short* __restrict__ B, int ldb,
    int K, char* smem, f32x4_t acc[4][4]) {
    const int tid = threadIdx.x;
    const int wave = tid >> 6, lane = tid & 63;
    const int wm = wave >> 1, wn = wave & 1;
    const int fr = lane & 15, g = lane >> 4;

    const int scolB = ((lane & 3) * 16) ^ (((lane >> 3) & 3) << 4);
    const unsigned short* pA0 = A + (size_t)(wave * 16 + (lane >> 2)) * lda + (scolB >> 1);
    const unsigned short* pA1 = pA0 + (size_t)128 * lda;
    const unsigned short* pB0 = B + (size_t)(wave * 16 + (lane >> 2)) * ldb + (scolB >> 1);

    const int rswz = (g * 16) ^ (((fr >> 1) & 3) << 4);
    int offA[4], offB[4];
#pragma unroll
    for (int mi = 0; mi < 4; ++mi)
        offA[mi] = (wm * 64 + mi * 16 + fr) * 64 + rswz;
#pragma unroll
    for (int ni = 0; ni < 4; ++ni)
        offB[ni] = 16384 + (wn * 64 + ni * 16 + fr) * 64 + rswz;

#pragma unroll
    for (int mi = 0; mi < 4; ++mi)
#pragma unroll
        for (int ni = 0; ni < 4; ++ni)
            acc[mi][ni] = (f32x4_t){0.f, 0.f, 0.f, 0.f};

    const int NT = K >> 5;

    STAGE3(0, 0);
    STAGE3(1, 1);

    int cb = 0;
    for (int t = 0; t < NT; ++t) {
        if (t + 1 < NT) asm volatile("s_waitcnt vmcnt(3)" ::: "memory");
        else            asm volatile("s_waitcnt vmcnt(0)" ::: "memory");
        asm volatile("s_barrier" ::: "memory");
        if (t + 2 < NT) {
            int sb = cb + 2; if (sb >= 3) sb -= 3;
            STAGE3(t + 2, sb);
        }
        const char* rb = smem + cb * 24576;
        bf16x8_t af[4], bfv[4];
#pragma unroll
        for (int mi = 0; mi < 4; ++mi)
            af[mi] = *reinterpret_cast<const bf16x8_t*>(rb + offA[mi]);
#pragma unroll
        for (int ni = 0; ni < 4; ++ni)
            bfv[ni] = *reinterpret_cast<const bf16x8_t*>(rb + offB[ni]);
        __builtin_amdgcn_s_setprio(1);
#pragma unroll
        for (int mi = 0; mi < 4; ++mi)
#pragma unroll
            for (int ni = 0; ni < 4; ++ni)
                acc[mi][ni] = __builtin_amdgcn_mfma_f32_16x16x32_bf16(
                    af[mi], bfv[ni], acc[mi][ni], 0, 0, 0);
        __builtin_amdgcn_s_setprio(0);
        cb = (cb + 1 == 3) ? 0 : cb + 1;
    }
}

#define E128_IDX                                                \
    const int lane = threadIdx.x & 63, wave = threadIdx.x >> 6; \
    const int e_r0 = (wave >> 1) * 64 + (lane >> 4) * 4;        \
    const int e_c0 = (wave & 1) * 64 + (lane & 15);

#define E128_LOOP(...)                                          \
    _Pragma("unroll") for (int mi = 0; mi < 4; ++mi)            \
    _Pragma("unroll") for (int ni = 0; ni < 4; ++ni)            \
    _Pragma("unroll") for (int j = 0; j < 4; ++j) { __VA_ARGS__ }

// ===========================================================================
// ENGINE B (r8, 0 conflicts): 256x256, BK=64, 512 threads; 2 phases x 32
// MFMA per K-tile over 128x128 quadrants; 2 x 64KB LDS (1 block/CU).
// Counted waits vmcnt(2)/vmcnt(4) BEFORE their barrier. 128B-row swizzle.
// Used for: vt, scores, pv, proj (traffic-sensitive GEMMs; 256^2 minimizes
// (1/BM+1/BN); vt-on-A measured +26us in r12).
// ===========================================================================
#define STA(h, i)                                                              \
    __builtin_amdgcn_global_load_lds(                                         \
        (const AS1 void*)(pA + kof + (size_t)((h) * 128 + (i) * 8) * lda),    \
        (AS3 void*)(wb + (h) * 16384 + wave * 2048 + (i) * 1024), 16, 0, 0)
#define STB(h, i)                                                              \
    __builtin_amdgcn_global_load_lds(                                         \
        (const AS1 void*)(pB + kof + (size_t)((h) * 128 + (i) * 8) * ldb),    \
        (AS3 void*)(wb + 32768 + (h) * 16384 + wave * 2048 + (i) * 1024), 16, 0, 0)

#define READ_A(qm)                                                             \
    _Pragma("unroll") for (int mi = 0; mi < 4; ++mi)                           \
        _Pragma("unroll") for (int ks = 0; ks < 2; ++ks)                       \
            af[mi][ks] = *reinterpret_cast<const bf16x8_t*>(rb + offA[qm][mi][ks]);
#define READ_B(qn)                                                             \
    _Pragma("unroll") for (int ni = 0; ni < 2; ++ni)                           \
        _Pragma("unroll") for (int ks = 0; ks < 2; ++ks)                       \
            bf[qn][ni][ks] = *reinterpret_cast<const bf16x8_t*>(rb + offB[qn][ni][ks]);

#define MFMA_QUAD(qm, qn)                                                      \
    __builtin_amdgcn_s_setprio(1);                                             \
    _Pragma("unroll") for (int mi = 0; mi < 4; ++mi)                           \
        _Pragma("unroll") for (int ni = 0; ni < 2; ++ni) {                     \
            acc[qm][qn][mi][ni] = __builtin_amdgcn_mfma_f32_16x16x32_bf16(     \
                af[mi][0], bf[qn][ni][0], acc[qm][qn][mi][ni], 0, 0, 0);       \
            acc[qm][qn][mi][ni] = __builtin_amdgcn_mfma_f32_16x16x32_bf16(     \
                af[mi][1], bf[qn][ni][1], acc[qm][qn][mi][ni], 0, 0, 0);       \
        }                                                                      \
    __builtin_amdgcn_s_setprio(0);

template <bool LAST>
__device__ __forceinline__ void tile_step(
    const char* rb, char* wb, size_t kof,
    const unsigned short* pA, const unsigned short* pB, int lda, int ldb,
    int wave, const int offA[2][4][2], const int offB[2][2][2],
    f32x4_t acc[2][2][4][2]) {
    bf16x8_t af[4][2], bf[2][2][2];
    // ---- PhA: quadrants (0,0),(0,1); needs A0,B0,B1 of tile t
    asm volatile("s_waitcnt vmcnt(2)" ::: "memory");
    asm volatile("s_barrier" ::: "memory");
    if constexpr (!LAST) { STA(0, 0); STA(0, 1); STB(0, 0); STB(0, 1); }
    READ_A(0); READ_B(0); READ_B(1);
    MFMA_QUAD(0, 0);
    MFMA_QUAD(0, 1);
    // ---- PhB: quadrants (1,1),(1,0); needs A1 of tile t
    if constexpr (LAST) asm volatile("s_waitcnt vmcnt(0)" ::: "memory");
    else                asm volatile("s_waitcnt vmcnt(4)" ::: "memory");
    asm volatile("s_barrier" ::: "memory");
    if constexpr (!LAST) { STB(1, 0); STB(1, 1); STA(1, 0); STA(1, 1); }
    READ_A(1);
    MFMA_QUAD(1, 1);
    MFMA_QUAD(1, 0);
}

__device__ __forceinline__ void gemm_ml_256(
    const unsigned short* __restrict__ A, int lda,
    const unsigned short* __restrict__ B, int ldb,
    int K, char* smem, f32x4_t acc[2][2][4][2]) {
    const int tid = threadIdx.x;
    const int wave = tid >> 6, lane = tid & 63;
    const int wsm = (wave >> 2) & 1, wsn = wave & 3;
    const int fr = lane & 15, g = lane >> 4;
    const int srow8 = lane >> 3;
    const int scolB = ((lane & 7) * 16) ^ (srow8 << 4);

    const unsigned short* pA = A + (size_t)(wave * 16 + srow8) * lda + (scolB >> 1);
    const unsigned short* pB = B + (size_t)(wave * 16 + srow8) * ldb + (scolB >> 1);

    int offA[2][4][2], offB[2][2][2];
#pragma unroll
    for (int qm = 0; qm < 2; ++qm)
#pragma unroll
        for (int mi = 0; mi < 4; ++mi)
#pragma unroll
            for (int ks = 0; ks < 2; ++ks)
                offA[qm][mi][ks] = qm * 16384 + (wsm * 64 + mi * 16 + fr) * 128 +
                                   ((ks * 64 + g * 16) ^ ((fr & 7) << 4));
#pragma unroll
    for (int qn = 0; qn < 2; ++qn)
#pragma unroll
        for (int ni = 0; ni < 2; ++ni)
#pragma unroll
            for (int ks = 0; ks < 2; ++ks)
                offB[qn][ni][ks] = 32768 + qn * 16384 + (wsn * 32 + ni * 16 + fr) * 128 +
                                   ((ks * 64 + g * 16) ^ ((fr & 7) << 4));

#pragma unroll
    for (int qm = 0; qm < 2; ++qm)
#pragma unroll
        for (int qn = 0; qn < 2; ++qn)
#pragma unroll
            for (int mi = 0; mi < 4; ++mi)
#pragma unroll
                for (int ni = 0; ni < 2; ++ni)
                    acc[qm][qn][mi][ni] = (f32x4_t){0.f, 0.f, 0.f, 0.f};

    const int NT = K >> 6;

    // prologue: stage tile 0 into buf0 in queue order A0, B0, B1, A1
    {
        char* wb = smem;
        const size_t kof = 0;
        STA(0, 0); STA(0, 1);
        STB(0, 0); STB(0, 1);
        STB(1, 0); STB(1, 1);
        STA(1, 0); STA(1, 1);
    }

    for (int t = 0; t < NT - 1; ++t) {
        const char* rb = smem + (size_t)(t & 1) * 65536;
        char* wb = smem + (size_t)((t & 1) ^ 1) * 65536;
        tile_step<false>(rb, wb, (size_t)(t + 1) * 64, pA, pB, lda, ldb,
                         wave, offA, offB, acc);
    }
    {
        const char* rb = smem + (size_t)((NT - 1) & 1) * 65536;
        tile_step<true>(rb, smem, 0, pA, pB, lda, ldb, wave, offA, offB, acc);
    }
}

#define E256_IDX                                                \
    const int lane = threadIdx.x & 63, wave = threadIdx.x >> 6; \
    const int e_r0 = ((wave >> 2) & 1) * 64 + (lane >> 4) * 4;  \
    const int e_c0 = (wave & 3) * 32 + (lane & 15);

#define E256_LOOP(...)                                          \
    _Pragma("unroll") for (int qm = 0; qm < 2; ++qm)            \
    _Pragma("unroll") for (int qn = 0; qn < 2; ++qn)            \
    _Pragma("unroll") for (int mi = 0; mi < 4; ++mi)            \
    _Pragma("unroll") for (int ni = 0; ni < 2; ++ni)            \
    _Pragma("unroll") for (int j = 0; j < 4; ++j) { __VA_ARGS__ }

// Interleaved q/k layout: per batch z (8 total), base elem z*4194304:
//   q_z[2048][1024] at +0, k_z[2048][1024] at +2097152.
// Softmax output P_z[2048][2048] bf16 later overlays exactly this region.

// ---------------------------------------------------------------------------
// QKV GEMM, Q/K half (ENGINE A): M=16384, N=2048, K=1024
// ---------------------------------------------------------------------------
__global__ __launch_bounds__(512, 4) void k_gemm_qkv_qk(
    const unsigned short* __restrict__ x, const unsigned short* __restrict__ w,
    unsigned short* __restrict__ qk) {
    __shared__ __align__(16) char smem[73728];
    const size_t tm = (size_t)blockIdx.x * 256, tn = (size_t)blockIdx.y * 128;
    f32x4_t acc[4][4];
    gemm_ml_128(x + tm * 1024, 1024, w + tn * 1024, 1024, 1024, smem, acc);
    E128_IDX
    E128_LOOP(
        size_t m = tm + e_r0 + mi * 16 + j;
        size_t z = m >> 11;
        size_t nloc = m & 2047;
        int n = (int)tn + e_c0 + ni * 16;
        unsigned short v = f2b(acc[mi][ni][j]);
        size_t base = z * 4194304 + nloc * 1024;
        if (n < 1024) qk[base + n] = v;
        else          qk[base + 2097152 + (n - 1024)] = v;
    )
}

// ---------------------------------------------------------------------------
// QKV GEMM, V^T half (ENGINE B, operands swapped): M=1024, N=16384, K=1024
// vt[c][token] = v[token][c], coalesced stores.
// ---------------------------------------------------------------------------
__global__ __launch_bounds__(512, 2) void k_gemm_vt(
    const unsigned short* __restrict__ wv, const unsigned short* __restrict__ x,
    unsigned short* __restrict__ vt) {
    __shared__ __align__(16) char smem[131072];
    const size_t tm = (size_t)blockIdx.x * 256, tn = (size_t)blockIdx.y * 256;
    f32x4_t acc[2][2][4][2];
    gemm_ml_256(wv + tm * 1024, 1024, x + tn * 1024, 1024, 1024, smem, acc);
    E256_IDX
    E256_LOOP(
        size_t m = tm + qm * 128 + e_r0 + mi * 16 + j;   // c
        size_t n = tn + qn * 128 + e_c0 + ni * 16;       // token
        vt[m * 16384 + n] = f2b(acc[qm][qn][mi][ni][j]);
    )
}

// ---------------------------------------------------------------------------
// Scores (ENGINE B): batch z = z0 + blockIdx.z; S = bf16((q·k)/32)
// ---------------------------------------------------------------------------
__global__ __launch_bounds__(512, 2) void k_gemm_scores(
    const unsigned short* __restrict__ qk, unsigned short* __restrict__ S, int z0) {
    __shared__ __align__(16) char smem[131072];
    const size_t z = z0 + blockIdx.z;
    const size_t tm = (size_t)blockIdx.x * 256, tn = (size_t)blockIdx.y * 256;
    const unsigned short* qz = qk + z * 4194304;
    const unsigned short* kz = qz + 2097152;
    f32x4_t acc[2][2][4][2];
    gemm_ml_256(qz + tm * 1024, 1024, kz + tn * 1024, 1024, 1024, smem, acc);
    E256_IDX
    unsigned short* Sz = S + (size_t)blockIdx.z * 4194304;
    E256_LOOP(
        size_t m = tm + qm * 128 + e_r0 + mi * 16 + j;
        size_t n = tn + qn * 128 + e_c0 + ni * 16;
        Sz[m * 2048 + n] = f2b(acc[qm][qn][mi][ni][j] * 0.03125f);
    )
}

// ---------------------------------------------------------------------------
// Row softmax: NZ*2048 rows x 2048, bf16 in -> bf16 out (P overlays q/k)
// ---------------------------------------------------------------------------
__global__ __launch_bounds__(256) void k_softmax(const unsigned short* __restrict__ S,
                                                 unsigned short* __restrict__ qk,
                                                 int z0) {
    const size_t r = blockIdx.x;
    const int t = threadIdx.x, wv = t >> 6, ln = t & 63;
    const uint4 u = reinterpret_cast<const uint4*>(S + r * 2048)[t];
    float vals[8];
    vals[0] = b2f((unsigned short)(u.x & 0xffff)); vals[1] = b2f((unsigned short)(u.x >> 16));
    vals[2] = b2f((unsigned short)(u.y & 0xffff)); vals[3] = b2f((unsigned short)(u.y >> 16));
    vals[4] = b2f((unsigned short)(u.z & 0xffff)); vals[5] = b2f((unsigned short)(u.z >> 16));
    vals[6] = b2f((unsigned short)(u.w & 0xffff)); vals[7] = b2f((unsigned short)(u.w >> 16));

    float mx = vals[0];
#pragma unroll
    for (int i = 1; i < 8; ++i) mx = fmaxf(mx, vals[i]);
#pragma unroll
    for (int i = 32; i > 0; i >>= 1) mx = fmaxf(mx, __shfl_xor(mx, i, 64));
    __shared__ float red[8];
    if (ln == 0) red[wv] = mx;
    __syncthreads();
    mx = fmaxf(fmaxf(red[0], red[1]), fmaxf(red[2], red[3]));

    float ex[8], s = 0.f;
#pragma unroll
    for (int i = 0; i < 8; ++i) { ex[i] = __expf(vals[i] - mx); s += ex[i]; }
#pragma unroll
    for (int i = 32; i > 0; i >>= 1) s += __shfl_xor(s, i, 64);
    if (ln == 0) red[4 + wv] = s;
    __syncthreads();
    s = (red[4] + red[5]) + (red[6] + red[7]);
    float inv = 1.0f / s;

    uint4 o;
    o.x = (unsigned)f2b(ex[0] * inv) | ((unsigned)f2b(ex[1] * inv) << 16);
    o.y = (unsigned)f2b(ex[2] * inv) | ((unsigned)f2b(ex[3] * inv) << 16);
    o.z = (unsigned)f2b(ex[4] * inv) | ((unsigned)f2b(ex[5] * inv) << 16);
    o.w = (unsigned)f2b(ex[6] * inv) | ((unsigned)f2b(ex[7] * inv) << 16);

    const size_t zg = z0 + (r >> 11), nloc = r & 2047;
    reinterpret_cast<uint4*>(qk + zg * 4194304 + nloc * 2048)[t] = o;
}

// ---------------------------------------------------------------------------
// PV as O^T (ENGINE B): O^T[c][n] = sum_m vt[c][m] * P[n][m]
// M=1024 (c), N=2048 (n), K=2048; scrambled coalesced stores.
// ---------------------------------------------------------------------------
__global__ __launch_bounds__(512, 2) void k_gemm_pv(
    const unsigned short* __restrict__ vt, const unsigned short* __restrict__ qk,
    unsigned short* __restrict__ ob, int z0) {
    __shared__ __align__(16) char smem[131072];
    const size_t z = z0 + blockIdx.z;
    const size_t tm = (size_t)blockIdx.x * 256, tn = (size_t)blockIdx.y * 256;
    const unsigned short* P = qk + z * 4194304;
    f32x4_t acc[2][2][4][2];
    gemm_ml_256(vt + tm * 16384 + z * 2048, 16384,
                P + tn * 2048, 2048, 2048, smem, acc);
    E256_IDX
    unsigned short* oz = ob + z * 2097152;
    E256_LOOP(
        size_t m = tm + qm * 128 + e_r0 + mi * 16 + j;   // c
        size_t n = tn + qn * 128 + e_c0 + ni * 16;       // token n within batch
        oz[(2 * m + (n >> 10)) * 1024 + (n & 1023)] = f2b(acc[qm][qn][mi][ni][j]);
    )
}

// ---------------------------------------------------------------------------
// Proj (ENGINE B): out[m][d] = sum_j o2[m][j] * w_proj[d][j] + b_proj[d]
// M=16384, N=1024, K=1024, fp32 out
// ---------------------------------------------------------------------------
__global__ __launch_bounds__(512, 2) void k_gemm_proj(
    const unsigned short* __restrict__ o2, const unsigned short* __restrict__ w,
    const float* __restrict__ bias, float* __restrict__ out) {
    __shared__ __align__(16) char smem[131072];
    const size_t tm = (size_t)blockIdx.x * 256, tn = (size_t)blockIdx.y * 256;
    f32x4_t acc[2][2][4][2];
    gemm_ml_256(o2 + tm * 1024, 1024, w + tn * 1024, 1024, 1024, smem, acc);
    E256_IDX
    E256_LOOP(
        size_t m = tm + qm * 128 + e_r0 + mi * 16 + j;
        size_t n = tn + qn * 128 + e_c0 + ni * 16;
        out[m * 1024 + n] = acc[qm][qn][mi][ni][j] + bias[n];
    )
}

// ---------------------------------------------------------------------------
extern "C" void kernel_launch(void* const* d_in, const int* in_sizes, int n_in,
                              void* d_out, int out_size, void* d_ws, size_t ws_size,
                              hipStream_t stream) {
    const float* x     = (const float*)d_in[0];
    const float* wqkv  = (const float*)d_in[1];
    const float* wproj = (const float*)d_in[2];
    const float* bproj = (const float*)d_in[3];
    float* out = (float*)d_out;
    char* ws = (char*)d_ws;

    // workspace layout (bytes):
    const size_t off_xb    = 0;             // 33,554,432 x bf16 (obuf overlays)
    const size_t off_wqkv  = 33554432;      //  6,291,456
    const size_t off_wproj = 39845888;      //  2,097,152
    const size_t off_qk    = 41943040;      // 67,108,864 interleaved q/k (P overlays)
    const size_t off_vt    = 109051904;     // 33,554,432
    const size_t off_S     = 142606336;     // NZ * 8,388,608 bf16 logits chunk
    // adaptive chunk: largest NZ in {8,4,2,1} that fits
    int NZ = 0;
    for (int c = 8; c >= 1; c >>= 1)
        if (off_S + (size_t)c * 8388608 <= ws_size) { NZ = c; break; }
    if (NZ == 0) return;  // fail loudly via absmax check

    unsigned short* xb     = (unsigned short*)(ws + off_xb);
    unsigned short* wqkvb  = (unsigned short*)(ws + off_wqkv);
    unsigned short* wprojb = (unsigned short*)(ws + off_wproj);
    unsigned short* qkb    = (unsigned short*)(ws + off_qk);
    unsigned short* vtb    = (unsigned short*)(ws + off_vt);
    unsigned short* Sb     = (unsigned short*)(ws + off_S);
    unsigned short* obuf   = (unsigned short*)(ws + off_xb);  // overlay

    k_f2b<<<16384, 256, 0, stream>>>(x, xb, 4194304);
    k_f2b<<<3072, 256, 0, stream>>>(wqkv, wqkvb, 786432);
    k_f2b<<<1024, 256, 0, stream>>>(wproj, wprojb, 262144);

    k_gemm_qkv_qk<<<dim3(64, 16), 512, 0, stream>>>(xb, wqkvb, qkb);
    k_gemm_vt<<<dim3(4, 64), 512, 0, stream>>>(wqkvb + (size_t)2048 * 1024, xb, vtb);

    for (int z0 = 0; z0 < 8; z0 += NZ) {
        k_gemm_scores<<<dim3(8, 8, NZ), 512, 0, stream>>>(qkb, Sb, z0);
        k_softmax<<<NZ * 2048, 256, 0, stream>>>(Sb, qkb, z0);
        k_gemm_pv<<<dim3(4, 8, NZ), 512, 0, stream>>>(vtb, qkb, obuf, z0);
    }
    k_gemm_proj<<<dim3(64, 4), 512, 0, stream>>>(obuf, wprojb, bproj, out);
}